// Round 15
// baseline (385.986 us; speedup 1.0000x reference)
//
#include <hip/hip_runtime.h>
#include <hip/hip_bf16.h>

typedef __hip_bfloat16 hbf16;
typedef __attribute__((ext_vector_type(8))) short short8;
typedef __attribute__((ext_vector_type(4))) float f32x4;
typedef __attribute__((ext_vector_type(2))) float f32x2;
typedef __attribute__((ext_vector_type(4))) float f32x4v;

static __device__ __forceinline__ unsigned short f2bits(float f) {
  hbf16 h = __float2bfloat16(f);
  return *reinterpret_cast<unsigned short*>(&h);
}

// ---------------- bucketed CSR build (LDS-binned two-pass partition) --------
// buckets of 512 dst nodes; staging entry = (dstLocal9 << 23) | src  (4B).

#define BSH2 9
#define CHUNK 8192

// per-chunk LDS histogram -> hist2d[chunk][b] (no atomics, no init needed)
__global__ __launch_bounds__(256) void k_hist2d(
    const int* __restrict__ dst, int e, int nbuk, int* __restrict__ hist2d) {
  __shared__ int hist[1024];
  int t = threadIdx.x;
  int e0 = blockIdx.x * CHUNK;
  int e1 = min(e, e0 + CHUNK);
  for (int b = t; b < nbuk; b += 256) hist[b] = 0;
  __syncthreads();
  for (int i = e0 + t; i < e1; i += 256)
    atomicAdd(&hist[__builtin_nontemporal_load(&dst[i]) >> BSH2], 1);
  __syncthreads();
  for (int b = t; b < nbuk; b += 256)
    hist2d[(size_t)blockIdx.x * nbuk + b] = hist[b];
}

// single block: column-wise exclusive prefix over chunks (in place) + bucket
// totals -> block scan -> bstart. Requires nbuk <= 256.
__global__ __launch_bounds__(256) void k_scanB2(
    int* __restrict__ hist2d, int nchunk, int nbuk, int e,
    int* __restrict__ bstart, int* __restrict__ rowStart, int n) {
  __shared__ int s[256];
  int b = threadIdx.x;
  int running = 0;
  if (b < nbuk) {
    for (int c = 0; c < nchunk; ++c) {
      size_t idx = (size_t)c * nbuk + b;
      int t = hist2d[idx];
      hist2d[idx] = running;
      running += t;
    }
  }
  s[b] = (b < nbuk) ? running : 0;
  __syncthreads();
  for (int off = 1; off < 256; off <<= 1) {
    int x = (b >= off) ? s[b - off] : 0;
    __syncthreads();
    s[b] += x;
    __syncthreads();
  }
  if (b < nbuk) bstart[b] = s[b] - running;
  if (b == 0) { bstart[nbuk] = e; rowStart[n] = e; }
}

// each block: scatter its chunk into reserved per-bucket runs (LDS cursors).
__global__ __launch_bounds__(256) void k_partA(
    const int* __restrict__ src, const int* __restrict__ dst, int e, int nbuk,
    const int* __restrict__ bstart, const int* __restrict__ hist2d,
    unsigned* __restrict__ staging) {
  __shared__ int pos[1024];
  int t = threadIdx.x;
  int e0 = blockIdx.x * CHUNK;
  int e1 = min(e, e0 + CHUNK);
  for (int b = t; b < nbuk; b += 256)
    pos[b] = bstart[b] + hist2d[(size_t)blockIdx.x * nbuk + b];
  __syncthreads();
  for (int i = e0 + t; i < e1; i += 256) {
    int d = __builtin_nontemporal_load(&dst[i]);
    int sv = __builtin_nontemporal_load(&src[i]);
    int b = d >> BSH2;
    int r = atomicAdd(&pos[b], 1);
    staging[r] = (unsigned)sv | ((unsigned)(d & 511) << 23);
  }
}

__global__ __launch_bounds__(512) void k_bucket_csr(
    const unsigned* __restrict__ staging, const int* __restrict__ bstart,
    int* __restrict__ rowStart, float* __restrict__ dinv, int* __restrict__ csr, int N) {
  __shared__ int hist[512];
  __shared__ int s[512];
  __shared__ int cnt[512];
  int b = blockIdx.x, t = threadIdx.x;
  int es = bstart[b], ee = bstart[b + 1];
  hist[t] = 0;
  __syncthreads();
  for (int i = es + t; i < ee; i += 512)
    atomicAdd(&hist[staging[i] >> 23], 1);
  __syncthreads();
  s[t] = hist[t];
  __syncthreads();
  for (int off = 1; off < 512; off <<= 1) {
    int x = (t >= off) ? s[t - off] : 0;
    __syncthreads();
    s[t] += x;
    __syncthreads();
  }
  int gpos = es + s[t] - hist[t];
  cnt[t] = gpos;
  int d = (b << BSH2) + t;
  if (d < N) {
    rowStart[d] = gpos;
    dinv[d] = rsqrtf((float)(hist[t] + 1));
  }
  __syncthreads();
  for (int i = es + t; i < ee; i += 512) {
    unsigned w = staging[i];
    int pos = atomicAdd(&cnt[w >> 23], 1);
    csr[pos] = (int)(w & 0x7fffffu);
  }
}

// transpose + cast the three weight matrices; tail threads zero gbuf.
__global__ void k_wt_all(const float* __restrict__ W0, const float* __restrict__ W1,
                         const float* __restrict__ W2, unsigned short* __restrict__ W0t,
                         unsigned short* __restrict__ W1t, unsigned short* __restrict__ W2t,
                         float* __restrict__ gbuf) {
  int i = blockIdx.x * blockDim.x + threadIdx.x;
  const float* W; unsigned short* Wt; int K, M, idx;
  if (i < 32768)       { W = W0; Wt = W0t; K = 128; M = 256; idx = i; }
  else if (i < 98304)  { W = W1; Wt = W1t; K = 256; M = 256; idx = i - 32768; }
  else if (i < 131072) { W = W2; Wt = W2t; K = 256; M = 128; idx = i - 98304; }
  else if (i < 147456) { gbuf[i - 131072] = 0.f; return; }
  else return;
  int m = idx / K, k = idx - m * K;
  Wt[idx] = f2bits(W[k * M + m]);
}

__global__ void k_cast_fp8(const float* __restrict__ x, const float* __restrict__ dinv,
                           unsigned* __restrict__ y, int n4) {
  int i = blockIdx.x * blockDim.x + threadIdx.x;
  if (i < n4) {
    float s = 16.f * dinv[i >> 5];
    f32x4v v = __builtin_nontemporal_load(reinterpret_cast<const f32x4v*>(x) + i);
    unsigned q = 0;
    q = __builtin_amdgcn_cvt_pk_fp8_f32(v[0] * s, v[1] * s, q, false);
    q = __builtin_amdgcn_cvt_pk_fp8_f32(v[2] * s, v[3] * s, q, true);
    y[i] = q;
  }
}

// ---------------- aggregation: wave-per-node fp8 gather-sum ------------------
// in: q = 16*dinv ⊙ h (fp8).  out fp8(scale16) = acc*dinv[d] (+16*bias).

template<int VPL>
static __device__ __forceinline__ unsigned agg8_load(
    const void* __restrict__ h8, int idx, int lane) {
  if constexpr (VPL == 4)
    return reinterpret_cast<const unsigned*>(h8)[(size_t)idx * 64 + lane];
  else
    return (unsigned)reinterpret_cast<const unsigned short*>(h8)[(size_t)idx * 64 + lane];
}

template<int VPL>
static __device__ __forceinline__ void agg8_add(unsigned v, float* acc) {
  f32x2 lo = __builtin_amdgcn_cvt_pk_f32_fp8(v, false);
  acc[0] += lo[0]; acc[1] += lo[1];
  if constexpr (VPL == 4) {
    f32x2 hi = __builtin_amdgcn_cvt_pk_f32_fp8(v, true);
    acc[2] += hi[0]; acc[3] += hi[1];
  }
}

template<int VPL, int U>
static __device__ __forceinline__ void agg8_chunk(
    const void* __restrict__ h8, const int* __restrict__ csr,
    int k, int lane, float* acc) {
  unsigned v[U];
#pragma unroll
  for (int u = 0; u < U; ++u) {
    int idx = __builtin_nontemporal_load(&csr[k + u]);
    v[u] = agg8_load<VPL>(h8, idx, lane);
  }
#pragma unroll
  for (int u = 0; u < U; ++u) agg8_add<VPL>(v[u], acc);
}

template<int D, int BIAS>
__global__ __launch_bounds__(256) void aggregate_f8(
    const void* __restrict__ h8, const int* __restrict__ csr,
    const int* __restrict__ rowStart, const float* __restrict__ dinv,
    const float* __restrict__ bias, void* __restrict__ outv, int N) {
  constexpr int VPL = D / 64;
  int lane = threadIdx.x & 63;
  int d = (blockIdx.x * 256 + threadIdx.x) >> 6;
  if (d >= N) return;
  int rs = __builtin_amdgcn_readfirstlane(rowStart[d]);
  int re = __builtin_amdgcn_readfirstlane(rowStart[d + 1]);

  float acc[VPL] = {};
  agg8_add<VPL>(agg8_load<VPL>(h8, d, lane), acc);   // self loop

  int k = rs;
  for (; k + 16 <= re; k += 16) agg8_chunk<VPL, 16>(h8, csr, k, lane, acc);
  if (k + 8 <= re) { agg8_chunk<VPL, 8>(h8, csr, k, lane, acc); k += 8; }
  if (k + 4 <= re) { agg8_chunk<VPL, 4>(h8, csr, k, lane, acc); k += 4; }
  for (; k < re; ++k) {
    int idx = __builtin_nontemporal_load(&csr[k]);
    agg8_add<VPL>(agg8_load<VPL>(h8, idx, lane), acc);
  }

  float dv = dinv[d];
  float v[VPL];
#pragma unroll
  for (int j = 0; j < VPL; ++j) {
    v[j] = acc[j] * dv;
    if (BIAS) v[j] += 16.f * bias[lane * VPL + j];
  }
  if constexpr (VPL == 4) {
    unsigned q = 0;
    q = __builtin_amdgcn_cvt_pk_fp8_f32(v[0], v[1], q, false);
    q = __builtin_amdgcn_cvt_pk_fp8_f32(v[2], v[3], q, true);
    reinterpret_cast<unsigned*>(outv)[(size_t)d * 64 + lane] = q;
  } else {
    unsigned q = __builtin_amdgcn_cvt_pk_fp8_f32(v[0], v[1], 0, false);
    reinterpret_cast<unsigned short*>(outv)[(size_t)d * 64 + lane] = (unsigned short)q;
  }
}

// ---------------- MFMA GEMM: A fp8(scale16), bf16 math, transposed epilogue -

#define GLD16(g, l) __builtin_amdgcn_global_load_lds(                         \
    (const __attribute__((address_space(1))) void*)(g),                       \
    (__attribute__((address_space(3))) void*)(l), 16, 0, 0)

static __device__ __forceinline__ void dq_store(uint4 v, char* lA, int r, int c8) {
  unsigned ow[8];
#pragma unroll
  for (int j = 0; j < 4; ++j) {
    unsigned w = (&v.x)[j];
    f32x2 lo = __builtin_amdgcn_cvt_pk_f32_fp8(w, false);
    f32x2 hi = __builtin_amdgcn_cvt_pk_f32_fp8(w, true);
    ow[2 * j]     = (unsigned)f2bits(lo[0]) | ((unsigned)f2bits(lo[1]) << 16);
    ow[2 * j + 1] = (unsigned)f2bits(hi[0]) | ((unsigned)f2bits(hi[1]) << 16);
  }
  int s0 = (c8 * 2) ^ (r & 7);
  int s1 = (c8 * 2 + 1) ^ (r & 7);
  *reinterpret_cast<uint4*>(lA + r * 128 + s0 * 16) = make_uint4(ow[0], ow[1], ow[2], ow[3]);
  *reinterpret_cast<uint4*>(lA + r * 128 + s1 * 16) = make_uint4(ow[4], ow[5], ow[6], ow[7]);
}

template<int K, int EPI>
__global__ __launch_bounds__(256) void gemm_mfma(
    const unsigned char* __restrict__ A8, const unsigned short* __restrict__ Bt,
    const float* __restrict__ bias, const float* __restrict__ dinv,
    unsigned char* __restrict__ C8, int N, int M) {
  __shared__ __align__(16) char smem[32768];
  char* lA = smem;
  char* lB = smem + 16384;
  int tid = threadIdx.x, lane = tid & 63, wid = tid >> 6;
  int rowBase = blockIdx.x * 128, colBase = blockIdx.y * 128;
  int wr = (wid >> 1) * 64, wc = (wid & 1) * 64;

  f32x4 zero = {0.f, 0.f, 0.f, 0.f};
  f32x4 acc[4][4];
#pragma unroll
  for (int m = 0; m < 4; ++m)
#pragma unroll
    for (int n = 0; n < 4; ++n) acc[m][n] = zero;

  const char* Bb = (const char*)Bt;
  int ar = tid >> 1, ah = tid & 1;
  int ga = min(rowBase + ar, N - 1);

  for (int k0 = 0; k0 < K; k0 += 64) {
#pragma unroll
    for (int r = 0; r < 4; ++r) {
      int pbase = r * 256 + wid * 64;
      int p = pbase + lane;
      int row = p >> 3;
      int offg = ((p & 7) * 16) ^ ((row & 7) << 4);
      int gb = colBase + row;
      GLD16(Bb + (size_t)gb * (K * 2) + k0 * 2 + offg, lB + pbase * 16);
    }
    {
      const unsigned char* Ap = A8 + (size_t)ga * K + k0 + ah * 32;
      uint4 va = *reinterpret_cast<const uint4*>(Ap);
      uint4 vb = *reinterpret_cast<const uint4*>(Ap + 16);
      dq_store(va, lA, ar, ah * 2);
      dq_store(vb, lA, ar, ah * 2 + 1);
    }
    __syncthreads();
    int l15 = lane & 15, lhi = lane >> 4;
#pragma unroll
    for (int kk = 0; kk < 2; ++kk) {
      short8 af[4], bfr[4];
      int koff = kk * 64 + lhi * 16;
#pragma unroll
      for (int m = 0; m < 4; ++m) {
        int row = wr + m * 16 + l15;
        af[m] = *reinterpret_cast<const short8*>(lA + row * 128 + (koff ^ ((row & 7) << 4)));
      }
#pragma unroll
      for (int n = 0; n < 4; ++n) {
        int col = wc + n * 16 + l15;
        bfr[n] = *reinterpret_cast<const short8*>(lB + col * 128 + (koff ^ ((col & 7) << 4)));
      }
#pragma unroll
      for (int m = 0; m < 4; ++m)
#pragma unroll
        for (int n = 0; n < 4; ++n)
          acc[m][n] = __builtin_amdgcn_mfma_f32_16x16x32_bf16(bfr[n], af[m], acc[m][n], 0, 0, 0);
    }
    __syncthreads();
  }

  int l15 = lane & 15, lhi = lane >> 4;
#pragma unroll
  for (int m = 0; m < 4; ++m) {
    int row = rowBase + wr + m * 16 + l15;
    if (row >= N) continue;
    float dq = 1.f;
    if (EPI == 2) dq = 16.f * dinv[row];
    else if (EPI == 3) dq = dinv[row];
#pragma unroll
    for (int n = 0; n < 4; ++n) {
      int col = colBase + wc + n * 16 + lhi * 4;
      float4 bv4 = make_float4(0.f, 0.f, 0.f, 0.f);
      if (EPI == 2 || EPI == 4) bv4 = *reinterpret_cast<const float4*>(bias + col);
      float v[4];
#pragma unroll
      for (int j = 0; j < 4; ++j) {
        float a16 = acc[m][n][j];
        float bj = (&bv4.x)[j];
        if (EPI == 2)      v[j] = fmaxf(fmaf(a16, 0.0625f, bj), 0.f) * dq;
        else if (EPI == 3) v[j] = a16 * dq;
        else               v[j] = fmaxf(a16 + 16.f * bj, 0.f);
      }
      unsigned q = 0;
      q = __builtin_amdgcn_cvt_pk_fp8_f32(v[0], v[1], q, false);
      q = __builtin_amdgcn_cvt_pk_fp8_f32(v[2], v[3], q, true);
      *reinterpret_cast<unsigned*>(C8 + (size_t)row * M + col) = q;
    }
  }
}

// ---------------- pooling (fp8 input, scale 16) ----------------

__global__ void pool_partial(const unsigned char* __restrict__ h8,
                             const int* __restrict__ batch, int N, float* gbuf) {
  int per = (N + gridDim.x - 1) / gridDim.x;
  int lo = blockIdx.x * per;
  int hi = min(N, lo + per);
  if (lo >= hi) return;
  int t = threadIdx.x;
  int cur = batch[lo];
  float acc = 0.f;
  for (int i = lo; i < hi; ++i) {
    int g = batch[i];
    if (g != cur) {
      atomicAdd(&gbuf[cur * 128 + t], acc);
      acc = 0.f;
      cur = g;
    }
    unsigned b = (unsigned)__builtin_nontemporal_load(&h8[(size_t)i * 128 + t]);
    f32x2 lo2 = __builtin_amdgcn_cvt_pk_f32_fp8(b, false);
    acc += lo2[0];
  }
  atomicAdd(&gbuf[cur * 128 + t], acc);
}

// ---------------- MLP head (computes its own graph bounds) ------------------

__global__ __launch_bounds__(256) void mlp(const float* __restrict__ gbuf,
                                           const int* __restrict__ batch, int N,
                                           const float* __restrict__ Wf1,
                                           const float* __restrict__ bf1,
                                           const float* __restrict__ Wf2,
                                           const float* __restrict__ bf2,
                                           float* __restrict__ out) {
  __shared__ float gs[128];
  __shared__ float hid[256];
  __shared__ int cnt_s;
  int b = blockIdx.x, t = threadIdx.x;
  if (t == 0) {
    int lo = 0, hi = N;
    while (lo < hi) { int mid = (lo + hi) >> 1; if (batch[mid] < b) lo = mid + 1; else hi = mid; }
    int l2 = lo, h2 = N;
    while (l2 < h2) { int mid = (l2 + h2) >> 1; if (batch[mid] < b + 1) l2 = mid + 1; else h2 = mid; }
    cnt_s = max(l2 - lo, 1);
  }
  __syncthreads();
  float inv = 0.0625f / (float)cnt_s;
  if (t < 128) gs[t] = gbuf[b * 128 + t] * inv;
  __syncthreads();
  float acc = bf1[t];
  for (int k = 0; k < 128; ++k) acc += gs[k] * Wf1[k * 256 + t];
  acc = fmaxf(acc, 0.f);
  hid[t] = acc * Wf2[t];
  __syncthreads();
  for (int s2 = 128; s2 > 0; s2 >>= 1) {
    if (t < s2) hid[t] += hid[t + s2];
    __syncthreads();
  }
  if (t == 0) out[b] = 1.f / (1.f + expf(-(hid[0] + bf2[0])));
}

// ---------------- launch ----------------

extern "C" void kernel_launch(void* const* d_in, const int* in_sizes, int n_in,
                              void* d_out, int out_size, void* d_ws, size_t ws_size,
                              hipStream_t stream) {
  const float* x   = (const float*)d_in[0];
  const int* ei    = (const int*)d_in[1];
  const int* batch = (const int*)d_in[2];
  const float* W0  = (const float*)d_in[3];
  const float* b0  = (const float*)d_in[4];
  const float* W1  = (const float*)d_in[5];
  const float* b1  = (const float*)d_in[6];
  const float* W2  = (const float*)d_in[7];
  const float* b2  = (const float*)d_in[8];
  const float* Wf1 = (const float*)d_in[9];
  const float* bf1 = (const float*)d_in[10];
  const float* Wf2 = (const float*)d_in[11];
  const float* bf2 = (const float*)d_in[12];
  float* out = (float*)d_out;

  const int DIN = 128, DH = 256, DOUT = 128, G = 128;
  const int N = in_sizes[0] / DIN;
  const int E = in_sizes[1] / 2;
  const int* src = ei;
  const int* dst = ei + E;
  const int NBUK = (N + 511) >> BSH2;         // 196 for N=100000 (<=256 req'd)
  const int NCHUNK = (E + CHUNK - 1) / CHUNK; // 196 for E=1.6M

  char* p = (char*)d_ws;
  auto alloc = [&](size_t bytes) {
    char* r = p;
    p += (bytes + 255) & ~(size_t)255;
    return r;
  };
  int* hist2d   = (int*)alloc((size_t)NCHUNK * NBUK * 4);
  int* bstart   = (int*)alloc((size_t)(NBUK + 1) * 4);
  int* rowStart = (int*)alloc((size_t)(N + 1) * 4);
  float* dinv   = (float*)alloc((size_t)N * 4);
  int* csr      = (int*)alloc((size_t)E * 4);
  float* gbuf   = (float*)alloc((size_t)G * DOUT * 4);
  unsigned short* W0t = (unsigned short*)alloc((size_t)DIN * DH * 2);
  unsigned short* W1t = (unsigned short*)alloc((size_t)DH * DH * 2);
  unsigned short* W2t = (unsigned short*)alloc((size_t)DH * DOUT * 2);
  char* S1 = (char*)alloc((size_t)N * DH * 2);
  char* S2 = (char*)alloc((size_t)N * DH * 2);

  unsigned* staging = (unsigned*)S2;

  unsigned*      xb8     = (unsigned*)S1;       // [N,128] fp8  16*dinv*x
  unsigned char* agg0_8  = (unsigned char*)S2;  // [N,128] fp8
  unsigned char* h1s8    = (unsigned char*)S1;  // [N,256] fp8  16*dinv*h1
  unsigned char* agg1_8  = (unsigned char*)S2;  // [N,256] fp8
  unsigned char* h2_8    = (unsigned char*)S1;  // [N,256] fp8  16*h2
  unsigned char* t2s8    = (unsigned char*)S2;  // [N,128] fp8  16*dinv*(h2 W2)
  unsigned char* aggout8 = (unsigned char*)S1;  // [N,128] fp8  16*(agg2+b2)

  const int tb = 256;

  k_hist2d<<<NCHUNK, 256, 0, stream>>>(dst, E, NBUK, hist2d);
  k_scanB2<<<1, 256, 0, stream>>>(hist2d, NCHUNK, NBUK, E, bstart, rowStart, N);
  k_partA<<<NCHUNK, 256, 0, stream>>>(src, dst, E, NBUK, bstart, hist2d, staging);
  k_bucket_csr<<<NBUK, 512, 0, stream>>>(staging, bstart, rowStart, dinv, csr, N);

  k_wt_all<<<(147456 + tb - 1) / tb, tb, 0, stream>>>(W0, W1, W2, W0t, W1t, W2t, gbuf);

  int n4 = N * DIN / 4;
  k_cast_fp8<<<(n4 + tb - 1) / tb, tb, 0, stream>>>(x, dinv, xb8, n4);

  int gx = (N + 127) / 128;
  int ga = (N + 3) / 4;

  // layer 0: agg(fp8)->fp8 A, GEMM 128->256 +b0+relu -> fp8(16*dinv)
  aggregate_f8<128, 0><<<ga, 256, 0, stream>>>(xb8, csr, rowStart, dinv, nullptr, agg0_8, N);
  gemm_mfma<128, 2><<<dim3(gx, 2), 256, 0, stream>>>(agg0_8, W0t, b0, dinv, h1s8, N, DH);

  // layer 1: agg(fp8)->fp8 A, GEMM 256->256 +b1+relu -> fp8(scale16)
  aggregate_f8<256, 0><<<ga, 256, 0, stream>>>(h1s8, csr, rowStart, dinv, nullptr, agg1_8, N);
  gemm_mfma<256, 4><<<dim3(gx, 2), 256, 0, stream>>>(agg1_8, W1t, b1, nullptr, h2_8, N, DH);

  // layer 2: GEMM 256->128 -> fp8(16*dinv), agg(fp8)+16*b2 -> fp8
  gemm_mfma<256, 3><<<dim3(gx, 1), 256, 0, stream>>>(h2_8, W2t, nullptr, dinv, t2s8, N, DOUT);
  aggregate_f8<128, 1><<<ga, 256, 0, stream>>>(t2s8, csr, rowStart, dinv, b2, aggout8, N);

  pool_partial<<<1000, 128, 0, stream>>>(aggout8, batch, N, gbuf);
  mlp<<<G, 256, 0, stream>>>(gbuf, batch, N, Wf1, bf1, Wf2, bf2, out);
}

// Round 16
// 350.232 us; speedup vs baseline: 1.1021x; 1.1021x over previous
//
#include <hip/hip_runtime.h>
#include <hip/hip_bf16.h>

typedef __hip_bfloat16 hbf16;
typedef __attribute__((ext_vector_type(8))) short short8;
typedef __attribute__((ext_vector_type(4))) float f32x4;
typedef __attribute__((ext_vector_type(2))) float f32x2;
typedef __attribute__((ext_vector_type(4))) float f32x4v;

static __device__ __forceinline__ unsigned short f2bits(float f) {
  hbf16 h = __float2bfloat16(f);
  return *reinterpret_cast<unsigned short*>(&h);
}

// ---------------- bucketed CSR build (LDS-binned two-pass partition) --------
// buckets of 512 dst nodes; staging entry = (dstLocal9 << 23) | src  (4B).

#define BSH2 9
#define CHUNK 8192

// per-chunk LDS histogram; ONE global atomic per (chunk,bucket) whose return
// value is the chunk's reservation offset within the bucket.
__global__ __launch_bounds__(256) void k_bcnt(
    const int* __restrict__ dst, int e, int nbuk,
    int* __restrict__ bcnt, int* __restrict__ blockOff) {
  __shared__ int hist[1024];
  int t = threadIdx.x;
  int e0 = blockIdx.x * CHUNK;
  int e1 = min(e, e0 + CHUNK);
  for (int b = t; b < nbuk; b += 256) hist[b] = 0;
  __syncthreads();
  for (int i = e0 + t; i < e1; i += 256)
    atomicAdd(&hist[__builtin_nontemporal_load(&dst[i]) >> BSH2], 1);
  __syncthreads();
  for (int b = t; b < nbuk; b += 256) {
    int h = hist[b];
    blockOff[(size_t)blockIdx.x * nbuk + b] = h ? atomicAdd(&bcnt[b], h) : 0;
  }
}

__global__ __launch_bounds__(1024) void k_scanB(
    const int* __restrict__ bcnt, int nbuk, int e,
    int* __restrict__ bstart, int* __restrict__ rowStart, int n) {
  __shared__ int s[1024];
  int t = threadIdx.x;
  int v = (t < nbuk) ? bcnt[t] : 0;
  s[t] = v;
  __syncthreads();
  for (int off = 1; off < 1024; off <<= 1) {
    int x = (t >= off) ? s[t - off] : 0;
    __syncthreads();
    s[t] += x;
    __syncthreads();
  }
  if (t < nbuk) bstart[t] = s[t] - v;
  if (t == 0) { bstart[nbuk] = e; rowStart[n] = e; }
}

__global__ __launch_bounds__(256) void k_partA(
    const int* __restrict__ src, const int* __restrict__ dst, int e, int nbuk,
    const int* __restrict__ bstart, const int* __restrict__ blockOff,
    unsigned* __restrict__ staging) {
  __shared__ int pos[1024];
  int t = threadIdx.x;
  int e0 = blockIdx.x * CHUNK;
  int e1 = min(e, e0 + CHUNK);
  for (int b = t; b < nbuk; b += 256)
    pos[b] = bstart[b] + blockOff[(size_t)blockIdx.x * nbuk + b];
  __syncthreads();
  for (int i = e0 + t; i < e1; i += 256) {
    int d = __builtin_nontemporal_load(&dst[i]);
    int sv = __builtin_nontemporal_load(&src[i]);
    int b = d >> BSH2;
    int r = atomicAdd(&pos[b], 1);
    staging[r] = (unsigned)sv | ((unsigned)(d & 511) << 23);
  }
}

__global__ __launch_bounds__(512) void k_bucket_csr(
    const unsigned* __restrict__ staging, const int* __restrict__ bstart,
    int* __restrict__ rowStart, float* __restrict__ dinv, int* __restrict__ csr, int N) {
  __shared__ int hist[512];
  __shared__ int s[512];
  __shared__ int cnt[512];
  int b = blockIdx.x, t = threadIdx.x;
  int es = bstart[b], ee = bstart[b + 1];
  hist[t] = 0;
  __syncthreads();
  for (int i = es + t; i < ee; i += 512)
    atomicAdd(&hist[staging[i] >> 23], 1);
  __syncthreads();
  s[t] = hist[t];
  __syncthreads();
  for (int off = 1; off < 512; off <<= 1) {
    int x = (t >= off) ? s[t - off] : 0;
    __syncthreads();
    s[t] += x;
    __syncthreads();
  }
  int gpos = es + s[t] - hist[t];
  cnt[t] = gpos;
  int d = (b << BSH2) + t;
  if (d < N) {
    rowStart[d] = gpos;
    dinv[d] = rsqrtf((float)(hist[t] + 1));
  }
  __syncthreads();
  for (int i = es + t; i < ee; i += 512) {
    unsigned w = staging[i];
    int pos = atomicAdd(&cnt[w >> 23], 1);
    csr[pos] = (int)(w & 0x7fffffu);
  }
}

// transpose + cast all three weight matrices (weights stay bf16).
__global__ void k_wt_all(const float* __restrict__ W0, const float* __restrict__ W1,
                         const float* __restrict__ W2, unsigned short* __restrict__ W0t,
                         unsigned short* __restrict__ W1t, unsigned short* __restrict__ W2t) {
  int i = blockIdx.x * blockDim.x + threadIdx.x;
  const float* W; unsigned short* Wt; int K, M, idx;
  if (i < 32768)       { W = W0; Wt = W0t; K = 128; M = 256; idx = i; }
  else if (i < 98304)  { W = W1; Wt = W1t; K = 256; M = 256; idx = i - 32768; }
  else if (i < 131072) { W = W2; Wt = W2t; K = 256; M = 128; idx = i - 98304; }
  else return;
  int m = idx / K, k = idx - m * K;
  Wt[idx] = f2bits(W[k * M + m]);
}

__global__ void k_cast_fp8(const float* __restrict__ x, const float* __restrict__ dinv,
                           unsigned* __restrict__ y, int n4) {
  int i = blockIdx.x * blockDim.x + threadIdx.x;
  if (i < n4) {
    float s = 16.f * dinv[i >> 5];
    f32x4v v = __builtin_nontemporal_load(reinterpret_cast<const f32x4v*>(x) + i);
    unsigned q = 0;
    q = __builtin_amdgcn_cvt_pk_fp8_f32(v[0] * s, v[1] * s, q, false);
    q = __builtin_amdgcn_cvt_pk_fp8_f32(v[2] * s, v[3] * s, q, true);
    y[i] = q;
  }
}

// ---------------- aggregation: wave-per-node fp8 gather-sum ------------------
// in: q = 16*dinv ⊙ h (fp8).  out fp8(scale16) = acc*dinv[d] (+16*bias).

template<int VPL>
static __device__ __forceinline__ unsigned agg8_load(
    const void* __restrict__ h8, int idx, int lane) {
  if constexpr (VPL == 4)
    return reinterpret_cast<const unsigned*>(h8)[(size_t)idx * 64 + lane];
  else
    return (unsigned)reinterpret_cast<const unsigned short*>(h8)[(size_t)idx * 64 + lane];
}

template<int VPL>
static __device__ __forceinline__ void agg8_add(unsigned v, float* acc) {
  f32x2 lo = __builtin_amdgcn_cvt_pk_f32_fp8(v, false);
  acc[0] += lo[0]; acc[1] += lo[1];
  if constexpr (VPL == 4) {
    f32x2 hi = __builtin_amdgcn_cvt_pk_f32_fp8(v, true);
    acc[2] += hi[0]; acc[3] += hi[1];
  }
}

template<int VPL, int U>
static __device__ __forceinline__ void agg8_chunk(
    const void* __restrict__ h8, const int* __restrict__ csr,
    int k, int lane, float* acc) {
  unsigned v[U];
#pragma unroll
  for (int u = 0; u < U; ++u) {
    int idx = __builtin_nontemporal_load(&csr[k + u]);
    v[u] = agg8_load<VPL>(h8, idx, lane);
  }
#pragma unroll
  for (int u = 0; u < U; ++u) agg8_add<VPL>(v[u], acc);
}

template<int D, int BIAS>
__global__ __launch_bounds__(256) void aggregate_f8(
    const void* __restrict__ h8, const int* __restrict__ csr,
    const int* __restrict__ rowStart, const float* __restrict__ dinv,
    const float* __restrict__ bias, void* __restrict__ outv, int N) {
  constexpr int VPL = D / 64;
  int lane = threadIdx.x & 63;
  int d = (blockIdx.x * 256 + threadIdx.x) >> 6;
  if (d >= N) return;
  int rs = __builtin_amdgcn_readfirstlane(rowStart[d]);
  int re = __builtin_amdgcn_readfirstlane(rowStart[d + 1]);

  float acc[VPL] = {};
  agg8_add<VPL>(agg8_load<VPL>(h8, d, lane), acc);   // self loop

  int k = rs;
  for (; k + 16 <= re; k += 16) agg8_chunk<VPL, 16>(h8, csr, k, lane, acc);
  if (k + 8 <= re) { agg8_chunk<VPL, 8>(h8, csr, k, lane, acc); k += 8; }
  if (k + 4 <= re) { agg8_chunk<VPL, 4>(h8, csr, k, lane, acc); k += 4; }
  for (; k < re; ++k) {
    int idx = __builtin_nontemporal_load(&csr[k]);
    agg8_add<VPL>(agg8_load<VPL>(h8, idx, lane), acc);
  }

  float dv = dinv[d];
  float v[VPL];
#pragma unroll
  for (int j = 0; j < VPL; ++j) {
    v[j] = acc[j] * dv;
    if (BIAS) v[j] += 16.f * bias[lane * VPL + j];
  }
  if constexpr (VPL == 4) {
    unsigned q = 0;
    q = __builtin_amdgcn_cvt_pk_fp8_f32(v[0], v[1], q, false);
    q = __builtin_amdgcn_cvt_pk_fp8_f32(v[2], v[3], q, true);
    reinterpret_cast<unsigned*>(outv)[(size_t)d * 64 + lane] = q;
  } else {
    unsigned q = __builtin_amdgcn_cvt_pk_fp8_f32(v[0], v[1], 0, false);
    reinterpret_cast<unsigned short*>(outv)[(size_t)d * 64 + lane] = (unsigned short)q;
  }
}

// ---------------- MFMA GEMM: A fp8(scale16), bf16 math, transposed epilogue -
// mfma(bfr, af) computes C^T fragments: lane holds ONE node row (lane&15) and
// 4 CONSECUTIVE output cols -> fp8 C written as one 4B store.

#define GLD16(g, l) __builtin_amdgcn_global_load_lds(                         \
    (const __attribute__((address_space(1))) void*)(g),                       \
    (__attribute__((address_space(3))) void*)(l), 16, 0, 0)

static __device__ __forceinline__ void dq_store(uint4 v, char* lA, int r, int c8) {
  unsigned ow[8];
#pragma unroll
  for (int j = 0; j < 4; ++j) {
    unsigned w = (&v.x)[j];
    f32x2 lo = __builtin_amdgcn_cvt_pk_f32_fp8(w, false);
    f32x2 hi = __builtin_amdgcn_cvt_pk_f32_fp8(w, true);
    ow[2 * j]     = (unsigned)f2bits(lo[0]) | ((unsigned)f2bits(lo[1]) << 16);
    ow[2 * j + 1] = (unsigned)f2bits(hi[0]) | ((unsigned)f2bits(hi[1]) << 16);
  }
  int s0 = (c8 * 2) ^ (r & 7);
  int s1 = (c8 * 2 + 1) ^ (r & 7);
  *reinterpret_cast<uint4*>(lA + r * 128 + s0 * 16) = make_uint4(ow[0], ow[1], ow[2], ow[3]);
  *reinterpret_cast<uint4*>(lA + r * 128 + s1 * 16) = make_uint4(ow[4], ow[5], ow[6], ow[7]);
}

template<int K, int EPI>
__global__ __launch_bounds__(256) void gemm_mfma(
    const unsigned char* __restrict__ A8, const unsigned short* __restrict__ Bt,
    const float* __restrict__ bias, const float* __restrict__ dinv,
    unsigned char* __restrict__ C8, int N, int M) {
  __shared__ __align__(16) char smem[32768];
  char* lA = smem;
  char* lB = smem + 16384;
  int tid = threadIdx.x, lane = tid & 63, wid = tid >> 6;
  int rowBase = blockIdx.x * 128, colBase = blockIdx.y * 128;
  int wr = (wid >> 1) * 64, wc = (wid & 1) * 64;

  f32x4 zero = {0.f, 0.f, 0.f, 0.f};
  f32x4 acc[4][4];
#pragma unroll
  for (int m = 0; m < 4; ++m)
#pragma unroll
    for (int n = 0; n < 4; ++n) acc[m][n] = zero;

  const char* Bb = (const char*)Bt;
  int ar = tid >> 1, ah = tid & 1;
  int ga = min(rowBase + ar, N - 1);

  for (int k0 = 0; k0 < K; k0 += 64) {
#pragma unroll
    for (int r = 0; r < 4; ++r) {
      int pbase = r * 256 + wid * 64;
      int p = pbase + lane;
      int row = p >> 3;
      int offg = ((p & 7) * 16) ^ ((row & 7) << 4);
      int gb = colBase + row;
      GLD16(Bb + (size_t)gb * (K * 2) + k0 * 2 + offg, lB + pbase * 16);
    }
    {
      const unsigned char* Ap = A8 + (size_t)ga * K + k0 + ah * 32;
      uint4 va = *reinterpret_cast<const uint4*>(Ap);
      uint4 vb = *reinterpret_cast<const uint4*>(Ap + 16);
      dq_store(va, lA, ar, ah * 2);
      dq_store(vb, lA, ar, ah * 2 + 1);
    }
    __syncthreads();
    int l15 = lane & 15, lhi = lane >> 4;
#pragma unroll
    for (int kk = 0; kk < 2; ++kk) {
      short8 af[4], bfr[4];
      int koff = kk * 64 + lhi * 16;
#pragma unroll
      for (int m = 0; m < 4; ++m) {
        int row = wr + m * 16 + l15;
        af[m] = *reinterpret_cast<const short8*>(lA + row * 128 + (koff ^ ((row & 7) << 4)));
      }
#pragma unroll
      for (int n = 0; n < 4; ++n) {
        int col = wc + n * 16 + l15;
        bfr[n] = *reinterpret_cast<const short8*>(lB + col * 128 + (koff ^ ((col & 7) << 4)));
      }
#pragma unroll
      for (int m = 0; m < 4; ++m)
#pragma unroll
        for (int n = 0; n < 4; ++n)
          acc[m][n] = __builtin_amdgcn_mfma_f32_16x16x32_bf16(bfr[n], af[m], acc[m][n], 0, 0, 0);
    }
    __syncthreads();
  }

  int l15 = lane & 15, lhi = lane >> 4;
#pragma unroll
  for (int m = 0; m < 4; ++m) {
    int row = rowBase + wr + m * 16 + l15;
    if (row >= N) continue;
    float dq = 1.f;
    if (EPI == 2) dq = 16.f * dinv[row];
    else if (EPI == 3) dq = dinv[row];
#pragma unroll
    for (int n = 0; n < 4; ++n) {
      int col = colBase + wc + n * 16 + lhi * 4;
      float4 bv4 = make_float4(0.f, 0.f, 0.f, 0.f);
      if (EPI == 2 || EPI == 4) bv4 = *reinterpret_cast<const float4*>(bias + col);
      float v[4];
#pragma unroll
      for (int j = 0; j < 4; ++j) {
        float a16 = acc[m][n][j];
        float bj = (&bv4.x)[j];
        if (EPI == 2)      v[j] = fmaxf(fmaf(a16, 0.0625f, bj), 0.f) * dq;
        else if (EPI == 3) v[j] = a16 * dq;
        else               v[j] = fmaxf(a16 + 16.f * bj, 0.f);
      }
      unsigned q = 0;
      q = __builtin_amdgcn_cvt_pk_fp8_f32(v[0], v[1], q, false);
      q = __builtin_amdgcn_cvt_pk_fp8_f32(v[2], v[3], q, true);
      *reinterpret_cast<unsigned*>(C8 + (size_t)row * M + col) = q;
    }
  }
}

// ---------------- pooling (fp8 input, scale 16) ----------------

__global__ void graph_bounds(const int* batch, int n, int g_cnt, int* gstart) {
  int g = blockIdx.x * blockDim.x + threadIdx.x;
  if (g > g_cnt) return;
  int lo = 0, hi = n;
  while (lo < hi) {
    int mid = (lo + hi) >> 1;
    if (batch[mid] < g) lo = mid + 1; else hi = mid;
  }
  gstart[g] = lo;
}

__global__ void pool_partial(const unsigned char* __restrict__ h8,
                             const int* __restrict__ batch, int N, float* gbuf) {
  int per = (N + gridDim.x - 1) / gridDim.x;
  int lo = blockIdx.x * per;
  int hi = min(N, lo + per);
  if (lo >= hi) return;
  int t = threadIdx.x;
  int cur = batch[lo];
  float acc = 0.f;
  for (int i = lo; i < hi; ++i) {
    int g = batch[i];
    if (g != cur) {
      atomicAdd(&gbuf[cur * 128 + t], acc);
      acc = 0.f;
      cur = g;
    }
    unsigned b = (unsigned)__builtin_nontemporal_load(&h8[(size_t)i * 128 + t]);
    f32x2 lo2 = __builtin_amdgcn_cvt_pk_f32_fp8(b, false);
    acc += lo2[0];
  }
  atomicAdd(&gbuf[cur * 128 + t], acc);
}

// ---------------- MLP head ----------------

__global__ __launch_bounds__(256) void mlp(const float* __restrict__ gbuf,
                                           const int* __restrict__ gstart,
                                           const float* __restrict__ Wf1,
                                           const float* __restrict__ bf1,
                                           const float* __restrict__ Wf2,
                                           const float* __restrict__ bf2,
                                           float* __restrict__ out) {
  __shared__ float gs[128];
  __shared__ float hid[256];
  int b = blockIdx.x, t = threadIdx.x;
  float inv = 0.0625f / (float)max(gstart[b + 1] - gstart[b], 1);
  if (t < 128) gs[t] = gbuf[b * 128 + t] * inv;
  __syncthreads();
  float acc = bf1[t];
  for (int k = 0; k < 128; ++k) acc += gs[k] * Wf1[k * 256 + t];
  acc = fmaxf(acc, 0.f);
  hid[t] = acc * Wf2[t];
  __syncthreads();
  for (int s2 = 128; s2 > 0; s2 >>= 1) {
    if (t < s2) hid[t] += hid[t + s2];
    __syncthreads();
  }
  if (t == 0) out[b] = 1.f / (1.f + expf(-(hid[0] + bf2[0])));
}

// ---------------- launch ----------------

extern "C" void kernel_launch(void* const* d_in, const int* in_sizes, int n_in,
                              void* d_out, int out_size, void* d_ws, size_t ws_size,
                              hipStream_t stream) {
  const float* x   = (const float*)d_in[0];
  const int* ei    = (const int*)d_in[1];
  const int* batch = (const int*)d_in[2];
  const float* W0  = (const float*)d_in[3];
  const float* b0  = (const float*)d_in[4];
  const float* W1  = (const float*)d_in[5];
  const float* b1  = (const float*)d_in[6];
  const float* W2  = (const float*)d_in[7];
  const float* b2  = (const float*)d_in[8];
  const float* Wf1 = (const float*)d_in[9];
  const float* bf1 = (const float*)d_in[10];
  const float* Wf2 = (const float*)d_in[11];
  const float* bf2 = (const float*)d_in[12];
  float* out = (float*)d_out;

  const int DIN = 128, DH = 256, DOUT = 128, G = 128;
  const int N = in_sizes[0] / DIN;
  const int E = in_sizes[1] / 2;
  const int* src = ei;
  const int* dst = ei + E;
  const int NBUK = (N + 511) >> BSH2;
  const int NCHUNK = (E + CHUNK - 1) / CHUNK;

  char* p = (char*)d_ws;
  auto alloc = [&](size_t bytes) {
    char* r = p;
    p += (bytes + 255) & ~(size_t)255;
    return r;
  };
  int* bcnt     = (int*)alloc((size_t)NBUK * 4);
  int* blockOff = (int*)alloc((size_t)NCHUNK * NBUK * 4);
  int* bstart   = (int*)alloc((size_t)(NBUK + 1) * 4);
  int* rowStart = (int*)alloc((size_t)(N + 1) * 4);
  float* dinv   = (float*)alloc((size_t)N * 4);
  int* csr      = (int*)alloc((size_t)E * 4);
  int* gstart   = (int*)alloc((size_t)(G + 1) * 4);
  float* gbuf   = (float*)alloc((size_t)G * DOUT * 4);
  unsigned short* W0t = (unsigned short*)alloc((size_t)DIN * DH * 2);
  unsigned short* W1t = (unsigned short*)alloc((size_t)DH * DH * 2);
  unsigned short* W2t = (unsigned short*)alloc((size_t)DH * DOUT * 2);
  char* S1 = (char*)alloc((size_t)N * DH * 2);
  char* S2 = (char*)alloc((size_t)N * DH * 2);

  unsigned* staging = (unsigned*)S2;

  unsigned*      xb8     = (unsigned*)S1;       // [N,128] fp8  16*dinv*x
  unsigned char* agg0_8  = (unsigned char*)S2;  // [N,128] fp8
  unsigned char* h1s8    = (unsigned char*)S1;  // [N,256] fp8  16*dinv*h1
  unsigned char* agg1_8  = (unsigned char*)S2;  // [N,256] fp8
  unsigned char* h2_8    = (unsigned char*)S1;  // [N,256] fp8  16*h2
  unsigned char* t2s8    = (unsigned char*)S2;  // [N,128] fp8  16*dinv*(h2 W2)
  unsigned char* aggout8 = (unsigned char*)S1;  // [N,128] fp8  16*(agg2+b2)

  const int tb = 256;
  hipMemsetAsync(bcnt, 0, (size_t)NBUK * 4, stream);
  hipMemsetAsync(gbuf, 0, (size_t)G * DOUT * 4, stream);

  k_bcnt<<<NCHUNK, 256, 0, stream>>>(dst, E, NBUK, bcnt, blockOff);
  k_scanB<<<1, 1024, 0, stream>>>(bcnt, NBUK, E, bstart, rowStart, N);
  k_partA<<<NCHUNK, 256, 0, stream>>>(src, dst, E, NBUK, bstart, blockOff, staging);
  k_bucket_csr<<<NBUK, 512, 0, stream>>>(staging, bstart, rowStart, dinv, csr, N);

  k_wt_all<<<(131072 + tb - 1) / tb, tb, 0, stream>>>(W0, W1, W2, W0t, W1t, W2t);

  int n4 = N * DIN / 4;
  k_cast_fp8<<<(n4 + tb - 1) / tb, tb, 0, stream>>>(x, dinv, xb8, n4);

  int gx = (N + 127) / 128;
  int ga = (N + 3) / 4;

  // layer 0: agg(fp8)->fp8 A, GEMM 128->256 +b0+relu -> fp8(16*dinv)
  aggregate_f8<128, 0><<<ga, 256, 0, stream>>>(xb8, csr, rowStart, dinv, nullptr, agg0_8, N);
  gemm_mfma<128, 2><<<dim3(gx, 2), 256, 0, stream>>>(agg0_8, W0t, b0, dinv, h1s8, N, DH);

  // layer 1: agg(fp8)->fp8 A, GEMM 256->256 +b1+relu -> fp8(scale16)
  aggregate_f8<256, 0><<<ga, 256, 0, stream>>>(h1s8, csr, rowStart, dinv, nullptr, agg1_8, N);
  gemm_mfma<256, 4><<<dim3(gx, 2), 256, 0, stream>>>(agg1_8, W1t, b1, nullptr, h2_8, N, DH);

  // layer 2: GEMM 256->128 -> fp8(16*dinv), agg(fp8)+16*b2 -> fp8
  gemm_mfma<256, 3><<<dim3(gx, 1), 256, 0, stream>>>(h2_8, W2t, nullptr, dinv, t2s8, N, DOUT);
  aggregate_f8<128, 1><<<ga, 256, 0, stream>>>(t2s8, csr, rowStart, dinv, b2, aggout8, N);

  graph_bounds<<<1, 256, 0, stream>>>(batch, N, G, gstart);
  pool_partial<<<1000, 128, 0, stream>>>(aggout8, batch, N, gbuf);
  mlp<<<G, 256, 0, stream>>>(gbuf, gstart, Wf1, bf1, Wf2, bf2, out);
}